// Round 1
// baseline (615.048 us; speedup 1.0000x reference)
//
#include <hip/hip_runtime.h>

typedef __bf16 bf16;
typedef __attribute__((ext_vector_type(8))) __bf16 bf16x8;
typedef __attribute__((ext_vector_type(4))) __bf16 bf16x4;
typedef __attribute__((ext_vector_type(4))) float f32x4;

static constexpr int Bc = 4, Tc = 2048, Dc = 1024, Hc = 16, HSc = 64, DFF = 4096;
static constexpr int Mrows = Bc * Tc;  // 8192

#define DEV __device__ __forceinline__

DEV void load_lds16(const void* g, void* l) {
  __builtin_amdgcn_global_load_lds(
      (const __attribute__((address_space(1))) void*)g,
      (__attribute__((address_space(3))) void*)l, 16, 0, 0);
}

// ---------------- weight repack: wq/wk/wv [H,D,HS] -> WqkvT [3072(n)][1024(k=d)] bf16
__global__ void repack_qkv_kernel(const float* __restrict__ wq,
                                  const float* __restrict__ wk,
                                  const float* __restrict__ wv,
                                  bf16* __restrict__ dst) {
  __shared__ float tile[64][65];
  const int dblk = blockIdx.x;  // 0..15 (d blocks)
  const int z = blockIdx.y;     // 0..47 = w*16+h
  const int w = z >> 4, h = z & 15;
  const float* src = (w == 0 ? wq : (w == 1 ? wk : wv)) + (size_t)h * Dc * HSc;
  const int tx = threadIdx.x, ty = threadIdx.y;
#pragma unroll
  for (int i = 0; i < 16; ++i)
    tile[ty + i * 4][tx] = src[(size_t)(dblk * 64 + ty + i * 4) * HSc + tx];
  __syncthreads();
#pragma unroll
  for (int i = 0; i < 16; ++i) {
    const int s = ty + i * 4;
    dst[((size_t)w * 1024 + h * 64 + s) * Dc + dblk * 64 + tx] = (bf16)tile[tx][s];
  }
}

// ---------------- generic [R][C] f32 -> [C][R] bf16 transpose
__global__ void transpose_to_bf16_kernel(const float* __restrict__ src,
                                         bf16* __restrict__ dst, int R, int C) {
  __shared__ float tile[64][65];
  const int r0 = blockIdx.x * 64, c0 = blockIdx.y * 64;
  const int tx = threadIdx.x, ty = threadIdx.y;
#pragma unroll
  for (int i = 0; i < 16; ++i)
    tile[ty + i * 4][tx] = src[(size_t)(r0 + ty + i * 4) * C + c0 + tx];
  __syncthreads();
#pragma unroll
  for (int i = 0; i < 16; ++i)
    dst[(size_t)(c0 + ty + i * 4) * R + r0 + tx] = (bf16)tile[tx][ty + i * 4];
}

// ---------------- LayerNorm row kernel: f32 in -> bf16 out
__global__ __launch_bounds__(256) void ln_kernel(const float* __restrict__ x,
                                                 const float* __restrict__ gam,
                                                 const float* __restrict__ bet,
                                                 bf16* __restrict__ out) {
  const int row = blockIdx.x;
  const int t = threadIdx.x;
  const float4 v = ((const float4*)(x + (size_t)row * Dc))[t];
  float s = v.x + v.y + v.z + v.w;
  float s2 = v.x * v.x + v.y * v.y + v.z * v.z + v.w * v.w;
#pragma unroll
  for (int m = 1; m < 64; m <<= 1) {
    s += __shfl_xor(s, m);
    s2 += __shfl_xor(s2, m);
  }
  __shared__ float red[8];
  const int wid = t >> 6;
  if ((t & 63) == 0) { red[wid * 2] = s; red[wid * 2 + 1] = s2; }
  __syncthreads();
  s = red[0] + red[2] + red[4] + red[6];
  s2 = red[1] + red[3] + red[5] + red[7];
  const float mean = s * (1.f / Dc);
  const float var = s2 * (1.f / Dc) - mean * mean;
  const float rstd = rsqrtf(var + 1e-5f);
  const float4 gv = ((const float4*)gam)[t];
  const float4 bv = ((const float4*)bet)[t];
  bf16x4 o;
  o[0] = (bf16)((v.x - mean) * rstd * gv.x + bv.x);
  o[1] = (bf16)((v.y - mean) * rstd * gv.y + bv.y);
  o[2] = (bf16)((v.z - mean) * rstd * gv.z + bv.z);
  o[3] = (bf16)((v.w - mean) * rstd * gv.w + bv.w);
  *(bf16x4*)(out + (size_t)row * Dc + t * 4) = o;
}

// ---------------- GEMM: C[M,N] = A[M,K](bf16) * BT[N,K](bf16), m97 structure.
// MODE 0: QKV -> q(scaled)/k as [bh,t,hs] bf16, v transposed -> vt [bh,hs,t]
// MODE 1: proj: out_f32 = acc + bias[n] + resid   (x1)
// MODE 2: ffn1: out_bf16 = relu(acc + bias[n])    (h)
// MODE 3: ffn2: out_f32 = acc + bias[n] + resid   (final out)
template <int MODE, int KTOT, int NSTRIDE>
__global__ __launch_bounds__(256, 2) void gemm_kernel(
    const bf16* __restrict__ A, const bf16* __restrict__ BT,
    const float* __restrict__ bias, const float* __restrict__ resid,
    float* __restrict__ outf, bf16* __restrict__ outb,
    bf16* __restrict__ qo, bf16* __restrict__ ko, bf16* __restrict__ vto) {
  __shared__ __attribute__((aligned(16))) bf16 As[128 * 32];
  __shared__ __attribute__((aligned(16))) bf16 Bs[128 * 32];
  const int tid = threadIdx.x;
  const int wid = tid >> 6, lane = tid & 63;
  const int g = lane >> 4, c = lane & 15;
  const int wr = wid >> 1, wc = wid & 1;
  const int bm = blockIdx.x, bn = blockIdx.y;

  f32x4 acc[4][4];
#pragma unroll
  for (int i = 0; i < 4; ++i)
#pragma unroll
    for (int j = 0; j < 4; ++j)
#pragma unroll
      for (int r = 0; r < 4; ++r) acc[i][j][r] = 0.f;

  const bf16* gA = A + (size_t)(bm * 128 + wid * 32 + (lane >> 2)) * KTOT + (lane & 3) * 8;
  const bf16* gB = BT + (size_t)(bn * 128 + wid * 32 + (lane >> 2)) * KTOT + (lane & 3) * 8;
  bf16* lA0 = &As[(wid * 32) * 32];
  bf16* lA1 = &As[(wid * 32 + 16) * 32];
  bf16* lB0 = &Bs[(wid * 32) * 32];
  bf16* lB1 = &Bs[(wid * 32 + 16) * 32];

  for (int kt = 0; kt < KTOT / 32; ++kt) {
    load_lds16(gA, lA0);
    load_lds16(gA + (size_t)16 * KTOT, lA1);
    load_lds16(gB, lB0);
    load_lds16(gB + (size_t)16 * KTOT, lB1);
    gA += 32;
    gB += 32;
    __syncthreads();
    bf16x8 af[4], bfr[4];
#pragma unroll
    for (int mi = 0; mi < 4; ++mi)
      af[mi] = *(const bf16x8*)&As[(wr * 64 + mi * 16 + c) * 32 + g * 8];
#pragma unroll
    for (int ni = 0; ni < 4; ++ni)
      bfr[ni] = *(const bf16x8*)&Bs[(wc * 64 + ni * 16 + c) * 32 + g * 8];
#pragma unroll
    for (int mi = 0; mi < 4; ++mi)
#pragma unroll
      for (int ni = 0; ni < 4; ++ni)
        acc[mi][ni] =
            __builtin_amdgcn_mfma_f32_16x16x32_bf16(af[mi], bfr[ni], acc[mi][ni], 0, 0, 0);
    __syncthreads();
  }

  // epilogue: lane holds rows m0+r (m0 = bm*128+wr*64+mi*16+g*4), col n = bn*128+wc*64+ni*16+c
#pragma unroll
  for (int ni = 0; ni < 4; ++ni) {
    const int n = bn * 128 + wc * 64 + ni * 16 + c;
    float bi = 0.f;
    if (MODE != 0) bi = bias[n];
#pragma unroll
    for (int mi = 0; mi < 4; ++mi) {
      const int m0 = bm * 128 + wr * 64 + mi * 16 + g * 4;
      if (MODE == 0) {
        const int w = n >> 10, n1 = n & 1023, h = n1 >> 6, sidx = n1 & 63;
        const int b = m0 >> 11, t0 = m0 & 2047;
        if (w == 0) {
#pragma unroll
          for (int r = 0; r < 4; ++r)
            qo[(size_t)(b * Hc + h) * (Tc * HSc) + (size_t)(t0 + r) * HSc + sidx] =
                (bf16)(acc[mi][ni][r] * 0.125f);
        } else if (w == 1) {
#pragma unroll
          for (int r = 0; r < 4; ++r)
            ko[(size_t)(b * Hc + h) * (Tc * HSc) + (size_t)(t0 + r) * HSc + sidx] =
                (bf16)acc[mi][ni][r];
        } else {
          bf16x4 pk;
#pragma unroll
          for (int r = 0; r < 4; ++r) pk[r] = (bf16)acc[mi][ni][r];
          *(bf16x4*)&vto[((size_t)(b * Hc + h) * HSc + sidx) * Tc + t0] = pk;
        }
      } else if (MODE == 1 || MODE == 3) {
#pragma unroll
        for (int r = 0; r < 4; ++r) {
          const size_t idx = (size_t)(m0 + r) * NSTRIDE + n;
          outf[idx] = acc[mi][ni][r] + bi + resid[idx];
        }
      } else {  // MODE 2
#pragma unroll
        for (int r = 0; r < 4; ++r)
          outb[(size_t)(m0 + r) * NSTRIDE + n] = (bf16)fmaxf(acc[mi][ni][r] + bi, 0.f);
      }
    }
  }
}

// ---------------- causal flash attention, 1 wave/block, 64x64 tiles
// q,k: [bh, t, hs] bf16 (q pre-scaled), vt: [bh, hs, t] bf16, ctx out: [b*t, h*64+d] bf16
__global__ __launch_bounds__(64, 1) void attn_kernel(const bf16* __restrict__ q,
                                                     const bf16* __restrict__ k,
                                                     const bf16* __restrict__ vt,
                                                     bf16* __restrict__ ctx) {
  __shared__ __attribute__((aligned(16))) bf16 P[64][72];  // pad 72 -> conflict-light b128 reads
  const int bh = blockIdx.x >> 5;
  const int qt = 31 - (blockIdx.x & 31);  // heavy tiles dispatch first
  const int lane = threadIdx.x;
  const int g = lane >> 4, c = lane & 15;
  const bf16* qb = q + ((size_t)bh * Tc + qt * 64) * HSc;
  const bf16* kb0 = k + (size_t)bh * Tc * HSc;
  const bf16* vb0 = vt + (size_t)bh * HSc * Tc;

  bf16x8 qf[4][2];
#pragma unroll
  for (int mi = 0; mi < 4; ++mi)
#pragma unroll
    for (int kk = 0; kk < 2; ++kk)
      qf[mi][kk] = *(const bf16x8*)&qb[(size_t)(mi * 16 + c) * HSc + kk * 32 + g * 8];

  f32x4 o[4][4];
  float mrow[4][4], lrow[4][4];
#pragma unroll
  for (int mi = 0; mi < 4; ++mi)
#pragma unroll
    for (int r = 0; r < 4; ++r) {
      mrow[mi][r] = -1e30f;
      lrow[mi][r] = 0.f;
#pragma unroll
      for (int di = 0; di < 4; ++di) o[mi][di][r] = 0.f;
    }

  for (int kt = 0; kt <= qt; ++kt) {
    const bf16* kb = kb0 + (size_t)kt * 64 * HSc;
    bf16x8 kf[4][2];
#pragma unroll
    for (int ni = 0; ni < 4; ++ni)
#pragma unroll
      for (int kk = 0; kk < 2; ++kk)
        kf[ni][kk] = *(const bf16x8*)&kb[(size_t)(ni * 16 + c) * HSc + kk * 32 + g * 8];
    f32x4 s[4][4];
#pragma unroll
    for (int mi = 0; mi < 4; ++mi)
#pragma unroll
      for (int ni = 0; ni < 4; ++ni)
#pragma unroll
        for (int r = 0; r < 4; ++r) s[mi][ni][r] = 0.f;
#pragma unroll
    for (int kk = 0; kk < 2; ++kk)
#pragma unroll
      for (int mi = 0; mi < 4; ++mi)
#pragma unroll
        for (int ni = 0; ni < 4; ++ni)
          s[mi][ni] = __builtin_amdgcn_mfma_f32_16x16x32_bf16(qf[mi][kk], kf[ni][kk],
                                                              s[mi][ni], 0, 0, 0);
    if (kt == qt) {  // causal mask on diagonal tile
#pragma unroll
      for (int mi = 0; mi < 4; ++mi)
#pragma unroll
        for (int ni = 0; ni < 4; ++ni)
#pragma unroll
          for (int r = 0; r < 4; ++r) {
            const int row = mi * 16 + g * 4 + r, col = ni * 16 + c;
            if (col > row) s[mi][ni][r] = -1e30f;
          }
    }
    // online softmax; write P (un-normalized, exp'd) to LDS as bf16
#pragma unroll
    for (int mi = 0; mi < 4; ++mi) {
#pragma unroll
      for (int r = 0; r < 4; ++r) {
        float mx = fmaxf(fmaxf(s[mi][0][r], s[mi][1][r]), fmaxf(s[mi][2][r], s[mi][3][r]));
#pragma unroll
        for (int msk = 1; msk < 16; msk <<= 1) mx = fmaxf(mx, __shfl_xor(mx, msk));
        const float mold = mrow[mi][r];
        const float mnew = fmaxf(mold, mx);
        const float alpha = __expf(mold - mnew);
        mrow[mi][r] = mnew;
        float rs = 0.f;
#pragma unroll
        for (int ni = 0; ni < 4; ++ni) {
          const float p = __expf(s[mi][ni][r] - mnew);
          rs += p;
          P[mi * 16 + g * 4 + r][ni * 16 + c] = (bf16)p;
        }
#pragma unroll
        for (int msk = 1; msk < 16; msk <<= 1) rs += __shfl_xor(rs, msk);
        lrow[mi][r] = lrow[mi][r] * alpha + rs;
#pragma unroll
        for (int di = 0; di < 4; ++di) o[mi][di][r] *= alpha;
      }
    }
    asm volatile("s_waitcnt lgkmcnt(0)" ::: "memory");
    __builtin_amdgcn_sched_barrier(0);
    // PV: ctx += P @ V   (A = P rows q, B = V cols d; vt gives contiguous kv per d-row)
    const bf16* vb = vb0 + kt * 64;
    bf16x8 vf[4][2], pf[4][2];
#pragma unroll
    for (int di = 0; di < 4; ++di)
#pragma unroll
      for (int kk = 0; kk < 2; ++kk)
        vf[di][kk] = *(const bf16x8*)&vb[(size_t)(di * 16 + c) * Tc + kk * 32 + g * 8];
#pragma unroll
    for (int mi = 0; mi < 4; ++mi)
#pragma unroll
      for (int kk = 0; kk < 2; ++kk)
        pf[mi][kk] = *(const bf16x8*)&P[mi * 16 + c][kk * 32 + g * 8];
#pragma unroll
    for (int kk = 0; kk < 2; ++kk)
#pragma unroll
      for (int mi = 0; mi < 4; ++mi)
#pragma unroll
        for (int di = 0; di < 4; ++di)
          o[mi][di] = __builtin_amdgcn_mfma_f32_16x16x32_bf16(pf[mi][kk], vf[di][kk],
                                                              o[mi][di], 0, 0, 0);
  }
  // normalize + store ctx
  const int b = bh >> 4, h = bh & 15;
#pragma unroll
  for (int mi = 0; mi < 4; ++mi)
#pragma unroll
    for (int r = 0; r < 4; ++r) {
      const int t = qt * 64 + mi * 16 + g * 4 + r;
      const float inv = 1.f / lrow[mi][r];
#pragma unroll
      for (int di = 0; di < 4; ++di)
        ctx[((size_t)(b * Tc + t)) * Dc + h * 64 + di * 16 + c] = (bf16)(o[mi][di][r] * inv);
    }
}

// ---------------- launch ----------------
extern "C" void kernel_launch(void* const* d_in, const int* in_sizes, int n_in,
                              void* d_out, int out_size, void* d_ws, size_t ws_size,
                              hipStream_t stream) {
  (void)in_sizes; (void)n_in; (void)out_size; (void)ws_size;
  const float* x      = (const float*)d_in[0];
  const float* ln1_g  = (const float*)d_in[1];
  const float* ln1_b  = (const float*)d_in[2];
  const float* wq     = (const float*)d_in[3];
  const float* wk     = (const float*)d_in[4];
  const float* wv     = (const float*)d_in[5];
  const float* w_proj = (const float*)d_in[6];
  const float* b_proj = (const float*)d_in[7];
  const float* ln2_g  = (const float*)d_in[8];
  const float* ln2_b  = (const float*)d_in[9];
  const float* w1     = (const float*)d_in[10];
  const float* b1     = (const float*)d_in[11];
  const float* w2     = (const float*)d_in[12];
  const float* b2     = (const float*)d_in[13];
  float* out = (float*)d_out;
  char* ws = (char*)d_ws;

  // workspace layout (bytes); hbuf aliases q/k/vt/ctx (dead by FFN1)
  bf16* qbuf   = (bf16*)(ws + 0);          // 16777216
  bf16* kbuf   = (bf16*)(ws + 16777216);   // 16777216
  bf16* vtbuf  = (bf16*)(ws + 33554432);   // 16777216
  bf16* ctxbuf = (bf16*)(ws + 50331648);   // 16777216
  bf16* wqkvT  = (bf16*)(ws + 67108864);   // 6291456
  bf16* hbuf   = (bf16*)(ws + 0);          // 67108864 (aliases the four above)
  bf16* wprojT = (bf16*)(ws + 73400320);   // 2097152
  bf16* w1T    = (bf16*)(ws + 75497472);   // 8388608
  bf16* w2T    = (bf16*)(ws + 83886080);   // 8388608
  bf16* xn     = (bf16*)(ws + 92274688);   // 16777216 (reused for ln1 and ln2 outputs)
  float* x1buf = (float*)(ws + 109051904); // 33554432  -> total 142606336

  // 1) weight repacks (all -> BT[N][K] bf16)
  repack_qkv_kernel<<<dim3(16, 48), dim3(64, 4), 0, stream>>>(wq, wk, wv, wqkvT);
  transpose_to_bf16_kernel<<<dim3(16, 16), dim3(64, 4), 0, stream>>>(w_proj, wprojT, 1024, 1024);
  transpose_to_bf16_kernel<<<dim3(16, 64), dim3(64, 4), 0, stream>>>(w1, w1T, 1024, 4096);
  transpose_to_bf16_kernel<<<dim3(64, 16), dim3(64, 4), 0, stream>>>(w2, w2T, 4096, 1024);

  // 2) LN1
  ln_kernel<<<Mrows, 256, 0, stream>>>(x, ln1_g, ln1_b, xn);
  // 3) QKV projection (N=3072)
  gemm_kernel<0, 1024, 0><<<dim3(64, 24), 256, 0, stream>>>(
      xn, wqkvT, nullptr, nullptr, nullptr, nullptr, qbuf, kbuf, vtbuf);
  // 4) attention
  attn_kernel<<<Bc * Hc * 32, 64, 0, stream>>>(qbuf, kbuf, vtbuf, ctxbuf);
  // 5) out-proj + residual
  gemm_kernel<1, 1024, 1024><<<dim3(64, 8), 256, 0, stream>>>(
      ctxbuf, wprojT, b_proj, x, x1buf, nullptr, nullptr, nullptr, nullptr);
  // 6) LN2
  ln_kernel<<<Mrows, 256, 0, stream>>>(x1buf, ln2_g, ln2_b, xn);
  // 7) FFN1 (relu)
  gemm_kernel<2, 1024, 4096><<<dim3(64, 32), 256, 0, stream>>>(
      xn, w1T, b1, nullptr, nullptr, hbuf, nullptr, nullptr, nullptr);
  // 8) FFN2 + residual -> out
  gemm_kernel<3, 4096, 1024><<<dim3(64, 8), 256, 0, stream>>>(
      hbuf, w2T, b2, x1buf, out, nullptr, nullptr, nullptr, nullptr);
}

// Round 2
// 457.505 us; speedup vs baseline: 1.3444x; 1.3444x over previous
//
#include <hip/hip_runtime.h>

typedef __bf16 bf16;
typedef __attribute__((ext_vector_type(8))) __bf16 bf16x8;
typedef __attribute__((ext_vector_type(4))) __bf16 bf16x4;
typedef __attribute__((ext_vector_type(4))) float f32x4;

static constexpr int Bc = 4, Tc = 2048, Dc = 1024, Hc = 16, HSc = 64, DFF = 4096;
static constexpr int Mrows = Bc * Tc;  // 8192

#define DEV __device__ __forceinline__

DEV void load_lds16(const void* g, void* l) {
  __builtin_amdgcn_global_load_lds(
      (const __attribute__((address_space(1))) void*)g,
      (__attribute__((address_space(3))) void*)l, 16, 0, 0);
}

// ---------------- weight repack: wq/wk/wv [H,D,HS] -> WqkvT [3072(n)][1024(k=d)] bf16
__global__ void repack_qkv_kernel(const float* __restrict__ wq,
                                  const float* __restrict__ wk,
                                  const float* __restrict__ wv,
                                  bf16* __restrict__ dst) {
  __shared__ float tile[64][65];
  const int dblk = blockIdx.x;  // 0..15 (d blocks)
  const int z = blockIdx.y;     // 0..47 = w*16+h
  const int w = z >> 4, h = z & 15;
  const float* src = (w == 0 ? wq : (w == 1 ? wk : wv)) + (size_t)h * Dc * HSc;
  const int tx = threadIdx.x, ty = threadIdx.y;
#pragma unroll
  for (int i = 0; i < 16; ++i)
    tile[ty + i * 4][tx] = src[(size_t)(dblk * 64 + ty + i * 4) * HSc + tx];
  __syncthreads();
#pragma unroll
  for (int i = 0; i < 16; ++i) {
    const int s = ty + i * 4;
    dst[((size_t)w * 1024 + h * 64 + s) * Dc + dblk * 64 + tx] = (bf16)tile[tx][s];
  }
}

// ---------------- generic [R][C] f32 -> [C][R] bf16 transpose
__global__ void transpose_to_bf16_kernel(const float* __restrict__ src,
                                         bf16* __restrict__ dst, int R, int C) {
  __shared__ float tile[64][65];
  const int r0 = blockIdx.x * 64, c0 = blockIdx.y * 64;
  const int tx = threadIdx.x, ty = threadIdx.y;
#pragma unroll
  for (int i = 0; i < 16; ++i)
    tile[ty + i * 4][tx] = src[(size_t)(r0 + ty + i * 4) * C + c0 + tx];
  __syncthreads();
#pragma unroll
  for (int i = 0; i < 16; ++i)
    dst[(size_t)(c0 + ty + i * 4) * R + r0 + tx] = (bf16)tile[tx][ty + i * 4];
}

// ---------------- LayerNorm row kernel: f32 in -> bf16 out
__global__ __launch_bounds__(256) void ln_kernel(const float* __restrict__ x,
                                                 const float* __restrict__ gam,
                                                 const float* __restrict__ bet,
                                                 bf16* __restrict__ out) {
  const int row = blockIdx.x;
  const int t = threadIdx.x;
  const float4 v = ((const float4*)(x + (size_t)row * Dc))[t];
  float s = v.x + v.y + v.z + v.w;
  float s2 = v.x * v.x + v.y * v.y + v.z * v.z + v.w * v.w;
#pragma unroll
  for (int m = 1; m < 64; m <<= 1) {
    s += __shfl_xor(s, m);
    s2 += __shfl_xor(s2, m);
  }
  __shared__ float red[8];
  const int wid = t >> 6;
  if ((t & 63) == 0) { red[wid * 2] = s; red[wid * 2 + 1] = s2; }
  __syncthreads();
  s = red[0] + red[2] + red[4] + red[6];
  s2 = red[1] + red[3] + red[5] + red[7];
  const float mean = s * (1.f / Dc);
  const float var = s2 * (1.f / Dc) - mean * mean;
  const float rstd = rsqrtf(var + 1e-5f);
  const float4 gv = ((const float4*)gam)[t];
  const float4 bv = ((const float4*)bet)[t];
  bf16x4 o;
  o[0] = (bf16)((v.x - mean) * rstd * gv.x + bv.x);
  o[1] = (bf16)((v.y - mean) * rstd * gv.y + bv.y);
  o[2] = (bf16)((v.z - mean) * rstd * gv.z + bv.z);
  o[3] = (bf16)((v.w - mean) * rstd * gv.w + bv.w);
  *(bf16x4*)(out + (size_t)row * Dc + t * 4) = o;
}

// ---------------- GEMM: C[M,N] = A[M,K](bf16) * BT[N,K](bf16), m97 structure.
template <int MODE, int KTOT, int NSTRIDE>
__global__ __launch_bounds__(256, 2) void gemm_kernel(
    const bf16* __restrict__ A, const bf16* __restrict__ BT,
    const float* __restrict__ bias, const float* __restrict__ resid,
    float* __restrict__ outf, bf16* __restrict__ outb,
    bf16* __restrict__ qo, bf16* __restrict__ ko, bf16* __restrict__ vto) {
  __shared__ __attribute__((aligned(16))) bf16 As[128 * 32];
  __shared__ __attribute__((aligned(16))) bf16 Bs[128 * 32];
  const int tid = threadIdx.x;
  const int wid = tid >> 6, lane = tid & 63;
  const int g = lane >> 4, c = lane & 15;
  const int wr = wid >> 1, wc = wid & 1;
  const int bm = blockIdx.x, bn = blockIdx.y;

  f32x4 acc[4][4];
#pragma unroll
  for (int i = 0; i < 4; ++i)
#pragma unroll
    for (int j = 0; j < 4; ++j)
#pragma unroll
      for (int r = 0; r < 4; ++r) acc[i][j][r] = 0.f;

  const bf16* gA = A + (size_t)(bm * 128 + wid * 32 + (lane >> 2)) * KTOT + (lane & 3) * 8;
  const bf16* gB = BT + (size_t)(bn * 128 + wid * 32 + (lane >> 2)) * KTOT + (lane & 3) * 8;
  bf16* lA0 = &As[(wid * 32) * 32];
  bf16* lA1 = &As[(wid * 32 + 16) * 32];
  bf16* lB0 = &Bs[(wid * 32) * 32];
  bf16* lB1 = &Bs[(wid * 32 + 16) * 32];

  for (int kt = 0; kt < KTOT / 32; ++kt) {
    load_lds16(gA, lA0);
    load_lds16(gA + (size_t)16 * KTOT, lA1);
    load_lds16(gB, lB0);
    load_lds16(gB + (size_t)16 * KTOT, lB1);
    gA += 32;
    gB += 32;
    __syncthreads();
    bf16x8 af[4], bfr[4];
#pragma unroll
    for (int mi = 0; mi < 4; ++mi)
      af[mi] = *(const bf16x8*)&As[(wr * 64 + mi * 16 + c) * 32 + g * 8];
#pragma unroll
    for (int ni = 0; ni < 4; ++ni)
      bfr[ni] = *(const bf16x8*)&Bs[(wc * 64 + ni * 16 + c) * 32 + g * 8];
#pragma unroll
    for (int mi = 0; mi < 4; ++mi)
#pragma unroll
      for (int ni = 0; ni < 4; ++ni)
        acc[mi][ni] =
            __builtin_amdgcn_mfma_f32_16x16x32_bf16(af[mi], bfr[ni], acc[mi][ni], 0, 0, 0);
    __syncthreads();
  }

#pragma unroll
  for (int ni = 0; ni < 4; ++ni) {
    const int n = bn * 128 + wc * 64 + ni * 16 + c;
    float bi = 0.f;
    if (MODE != 0) bi = bias[n];
#pragma unroll
    for (int mi = 0; mi < 4; ++mi) {
      const int m0 = bm * 128 + wr * 64 + mi * 16 + g * 4;
      if (MODE == 0) {
        const int w = n >> 10, n1 = n & 1023, h = n1 >> 6, sidx = n1 & 63;
        const int b = m0 >> 11, t0 = m0 & 2047;
        if (w == 0) {
#pragma unroll
          for (int r = 0; r < 4; ++r)
            qo[(size_t)(b * Hc + h) * (Tc * HSc) + (size_t)(t0 + r) * HSc + sidx] =
                (bf16)(acc[mi][ni][r] * 0.125f);
        } else if (w == 1) {
#pragma unroll
          for (int r = 0; r < 4; ++r)
            ko[(size_t)(b * Hc + h) * (Tc * HSc) + (size_t)(t0 + r) * HSc + sidx] =
                (bf16)acc[mi][ni][r];
        } else {
          bf16x4 pk;
#pragma unroll
          for (int r = 0; r < 4; ++r) pk[r] = (bf16)acc[mi][ni][r];
          *(bf16x4*)&vto[((size_t)(b * Hc + h) * HSc + sidx) * Tc + t0] = pk;
        }
      } else if (MODE == 1 || MODE == 3) {
#pragma unroll
        for (int r = 0; r < 4; ++r) {
          const size_t idx = (size_t)(m0 + r) * NSTRIDE + n;
          outf[idx] = acc[mi][ni][r] + bi + resid[idx];
        }
      } else {  // MODE 2
#pragma unroll
        for (int r = 0; r < 4; ++r)
          outb[(size_t)(m0 + r) * NSTRIDE + n] = (bf16)fmaxf(acc[mi][ni][r] + bi, 0.f);
      }
    }
  }
}

// ---------------- causal flash attention v2
// 1 wave/block, 32-row q-tiles, paired (heavy+light) for load balance,
// defer-max softmax (no cross-lane reduce in common path), K prefetch dbuf.
// q,k: [bh, t, hs] bf16 (q pre-scaled), vt: [bh, hs, t] bf16, ctx: [b*t, h*64+d] bf16
__global__ __launch_bounds__(64, 2) void attn_kernel(const bf16* __restrict__ q,
                                                     const bf16* __restrict__ k,
                                                     const bf16* __restrict__ vt,
                                                     bf16* __restrict__ ctx) {
  __shared__ __attribute__((aligned(16))) bf16 P[32][72];
  // XCD-grouped mapping: dispatch d -> logical L so each XCD sees 8 whole heads
  const int d0 = blockIdx.x;
  const int L = (d0 & 7) * 256 + (d0 >> 3);
  const int bh = L >> 5, w = L & 31;
  const int lane = threadIdx.x;
  const int g = lane >> 4, c = lane & 15;
  const bf16* qh = q + (size_t)bh * Tc * HSc;
  const bf16* kh = k + (size_t)bh * Tc * HSc;
  const bf16* vh = vt + (size_t)bh * HSc * Tc;
  const int b = bh >> 4, h = bh & 15;

  for (int half = 0; half < 2; ++half) {
    const int qt = half ? w : 63 - w;  // pair (63-w, w): 33 kv-tiles total per wave
    const int ktmax = (qt * 32 + 31) >> 6;
    const bf16* qb = qh + (size_t)qt * 32 * HSc;

    bf16x8 qf[2][2];
#pragma unroll
    for (int mi = 0; mi < 2; ++mi)
#pragma unroll
      for (int kk = 0; kk < 2; ++kk)
        qf[mi][kk] = *(const bf16x8*)&qb[(size_t)(mi * 16 + c) * HSc + kk * 32 + g * 8];

    f32x4 o[2][4];
    float m_[2][4], ls[2][4];
#pragma unroll
    for (int mi = 0; mi < 2; ++mi)
#pragma unroll
      for (int r = 0; r < 4; ++r) {
        m_[mi][r] = -1e30f;
        ls[mi][r] = 0.f;
#pragma unroll
        for (int di = 0; di < 4; ++di) o[mi][di][r] = 0.f;
      }

    auto loadK = [&](bf16x8 (&kf)[4][2], int kt) {
      const bf16* kb = kh + (size_t)kt * 64 * HSc;
#pragma unroll
      for (int ni = 0; ni < 4; ++ni)
#pragma unroll
        for (int kk = 0; kk < 2; ++kk)
          kf[ni][kk] = *(const bf16x8*)&kb[(size_t)(ni * 16 + c) * HSc + kk * 32 + g * 8];
    };

    auto body = [&](bf16x8 (&kf)[4][2], int kt) {
      // V loads issued first (independent -> latency hides under MFMA+VALU)
      const bf16* vb = vh + kt * 64;
      bf16x8 vf[4][2];
#pragma unroll
      for (int di = 0; di < 4; ++di)
#pragma unroll
        for (int kk = 0; kk < 2; ++kk)
          vf[di][kk] = *(const bf16x8*)&vb[(size_t)(di * 16 + c) * Tc + kk * 32 + g * 8];

      f32x4 s[2][4];
#pragma unroll
      for (int mi = 0; mi < 2; ++mi)
#pragma unroll
        for (int ni = 0; ni < 4; ++ni)
#pragma unroll
          for (int r = 0; r < 4; ++r) s[mi][ni][r] = 0.f;
      __builtin_amdgcn_s_setprio(1);
#pragma unroll
      for (int kk = 0; kk < 2; ++kk)
#pragma unroll
        for (int mi = 0; mi < 2; ++mi)
#pragma unroll
          for (int ni = 0; ni < 4; ++ni)
            s[mi][ni] = __builtin_amdgcn_mfma_f32_16x16x32_bf16(qf[mi][kk], kf[ni][kk],
                                                                s[mi][ni], 0, 0, 0);
      __builtin_amdgcn_s_setprio(0);

      if (kt == ktmax) {  // causal mask (only possibly-masked tile)
#pragma unroll
        for (int mi = 0; mi < 2; ++mi)
#pragma unroll
          for (int ni = 0; ni < 4; ++ni)
#pragma unroll
            for (int r = 0; r < 4; ++r) {
              const int row = qt * 32 + mi * 16 + g * 4 + r;
              const int col = kt * 64 + ni * 16 + c;
              if (col > row) s[mi][ni][r] = -1e30f;
            }
      }

      // defer-max online softmax: no cross-lane ops unless a row max grows >8
      float pm[2][4];
      int need = 0;
#pragma unroll
      for (int mi = 0; mi < 2; ++mi)
#pragma unroll
        for (int r = 0; r < 4; ++r) {
          pm[mi][r] = fmaxf(fmaxf(s[mi][0][r], s[mi][1][r]), fmaxf(s[mi][2][r], s[mi][3][r]));
          need |= (pm[mi][r] > m_[mi][r] + 8.f) ? 1 : 0;
        }
      if (__any(need)) {  // rare rescale path: true row-max via 4-step shfl
#pragma unroll
        for (int mi = 0; mi < 2; ++mi)
#pragma unroll
          for (int r = 0; r < 4; ++r) {
            float mx = pm[mi][r];
#pragma unroll
            for (int msk = 1; msk < 16; msk <<= 1) mx = fmaxf(mx, __shfl_xor(mx, msk));
            const float mn = fmaxf(m_[mi][r], mx);
            const float al = __expf(m_[mi][r] - mn);
            m_[mi][r] = mn;
            ls[mi][r] *= al;
#pragma unroll
            for (int di = 0; di < 4; ++di) o[mi][di][r] *= al;
          }
      }
#pragma unroll
      for (int mi = 0; mi < 2; ++mi)
#pragma unroll
        for (int r = 0; r < 4; ++r) {
          float ps = 0.f;
#pragma unroll
          for (int ni = 0; ni < 4; ++ni) {
            const float p = __expf(s[mi][ni][r] - m_[mi][r]);
            ps += p;
            P[mi * 16 + g * 4 + r][ni * 16 + c] = (bf16)p;
          }
          ls[mi][r] += ps;  // per-lane partial; cross-lane reduce deferred to end
        }
      asm volatile("s_waitcnt lgkmcnt(0)" ::: "memory");
      __builtin_amdgcn_sched_barrier(0);

      bf16x8 pf[2][2];
#pragma unroll
      for (int mi = 0; mi < 2; ++mi)
#pragma unroll
        for (int kk = 0; kk < 2; ++kk)
          pf[mi][kk] = *(const bf16x8*)&P[mi * 16 + c][kk * 32 + g * 8];
      __builtin_amdgcn_s_setprio(1);
#pragma unroll
      for (int kk = 0; kk < 2; ++kk)
#pragma unroll
        for (int mi = 0; mi < 2; ++mi)
#pragma unroll
          for (int di = 0; di < 4; ++di)
            o[mi][di] = __builtin_amdgcn_mfma_f32_16x16x32_bf16(pf[mi][kk], vf[di][kk],
                                                                o[mi][di], 0, 0, 0);
      __builtin_amdgcn_s_setprio(0);
    };

    bf16x8 kfA[4][2], kfB[4][2];
    loadK(kfA, 0);
    int kt = 0;
    while (true) {
      if (kt < ktmax) loadK(kfB, kt + 1);
      body(kfA, kt);
      if (kt >= ktmax) break;
      ++kt;
      if (kt < ktmax) loadK(kfA, kt + 1);
      body(kfB, kt);
      if (kt >= ktmax) break;
      ++kt;
    }

    // final: reduce per-lane partial sums over the 16 col-lanes, normalize, store
#pragma unroll
    for (int mi = 0; mi < 2; ++mi)
#pragma unroll
      for (int r = 0; r < 4; ++r) {
        float l = ls[mi][r];
#pragma unroll
        for (int msk = 1; msk < 16; msk <<= 1) l += __shfl_xor(l, msk);
        const float inv = 1.f / l;
        const int t = qt * 32 + mi * 16 + g * 4 + r;
#pragma unroll
        for (int di = 0; di < 4; ++di)
          ctx[((size_t)(b * Tc + t)) * Dc + h * 64 + di * 16 + c] =
              (bf16)(o[mi][di][r] * inv);
      }
  }
}

// ---------------- launch ----------------
extern "C" void kernel_launch(void* const* d_in, const int* in_sizes, int n_in,
                              void* d_out, int out_size, void* d_ws, size_t ws_size,
                              hipStream_t stream) {
  (void)in_sizes; (void)n_in; (void)out_size; (void)ws_size;
  const float* x      = (const float*)d_in[0];
  const float* ln1_g  = (const float*)d_in[1];
  const float* ln1_b  = (const float*)d_in[2];
  const float* wq     = (const float*)d_in[3];
  const float* wk     = (const float*)d_in[4];
  const float* wv     = (const float*)d_in[5];
  const float* w_proj = (const float*)d_in[6];
  const float* b_proj = (const float*)d_in[7];
  const float* ln2_g  = (const float*)d_in[8];
  const float* ln2_b  = (const float*)d_in[9];
  const float* w1     = (const float*)d_in[10];
  const float* b1     = (const float*)d_in[11];
  const float* w2     = (const float*)d_in[12];
  const float* b2     = (const float*)d_in[13];
  float* out = (float*)d_out;
  char* ws = (char*)d_ws;

  bf16* qbuf   = (bf16*)(ws + 0);          // 16777216
  bf16* kbuf   = (bf16*)(ws + 16777216);   // 16777216
  bf16* vtbuf  = (bf16*)(ws + 33554432);   // 16777216
  bf16* ctxbuf = (bf16*)(ws + 50331648);   // 16777216
  bf16* wqkvT  = (bf16*)(ws + 67108864);   // 6291456
  bf16* hbuf   = (bf16*)(ws + 0);          // 67108864 (aliases q/k/vt/ctx, dead by FFN1)
  bf16* wprojT = (bf16*)(ws + 73400320);   // 2097152
  bf16* w1T    = (bf16*)(ws + 75497472);   // 8388608
  bf16* w2T    = (bf16*)(ws + 83886080);   // 8388608
  bf16* xn     = (bf16*)(ws + 92274688);   // 16777216
  float* x1buf = (float*)(ws + 109051904); // 33554432

  repack_qkv_kernel<<<dim3(16, 48), dim3(64, 4), 0, stream>>>(wq, wk, wv, wqkvT);
  transpose_to_bf16_kernel<<<dim3(16, 16), dim3(64, 4), 0, stream>>>(w_proj, wprojT, 1024, 1024);
  transpose_to_bf16_kernel<<<dim3(16, 64), dim3(64, 4), 0, stream>>>(w1, w1T, 1024, 4096);
  transpose_to_bf16_kernel<<<dim3(64, 16), dim3(64, 4), 0, stream>>>(w2, w2T, 4096, 1024);

  ln_kernel<<<Mrows, 256, 0, stream>>>(x, ln1_g, ln1_b, xn);
  gemm_kernel<0, 1024, 0><<<dim3(64, 24), 256, 0, stream>>>(
      xn, wqkvT, nullptr, nullptr, nullptr, nullptr, qbuf, kbuf, vtbuf);
  attn_kernel<<<2048, 64, 0, stream>>>(qbuf, kbuf, vtbuf, ctxbuf);
  gemm_kernel<1, 1024, 1024><<<dim3(64, 8), 256, 0, stream>>>(
      ctxbuf, wprojT, b_proj, x, x1buf, nullptr, nullptr, nullptr, nullptr);
  ln_kernel<<<Mrows, 256, 0, stream>>>(x1buf, ln2_g, ln2_b, xn);
  gemm_kernel<2, 1024, 4096><<<dim3(64, 32), 256, 0, stream>>>(
      xn, w1T, b1, nullptr, nullptr, hbuf, nullptr, nullptr, nullptr);
  gemm_kernel<3, 4096, 1024><<<dim3(64, 8), 256, 0, stream>>>(
      hbuf, w2T, b2, x1buf, out, nullptr, nullptr, nullptr, nullptr);
}

// Round 3
// 392.240 us; speedup vs baseline: 1.5680x; 1.1664x over previous
//
#include <hip/hip_runtime.h>

typedef __bf16 bf16;
typedef __attribute__((ext_vector_type(8))) __bf16 bf16x8;
typedef __attribute__((ext_vector_type(4))) __bf16 bf16x4;
typedef __attribute__((ext_vector_type(4))) float f32x4;

static constexpr int Bc = 4, Tc = 2048, Dc = 1024, Hc = 16, HSc = 64, DFF = 4096;
static constexpr int Mrows = Bc * Tc;  // 8192

#define DEV __device__ __forceinline__

DEV void load_lds16(const void* g, void* l) {
  __builtin_amdgcn_global_load_lds(
      (const __attribute__((address_space(1))) void*)g,
      (__attribute__((address_space(3))) void*)l, 16, 0, 0);
}

// ---------------- weight repack: wq/wk/wv [H,D,HS] -> WqkvT [3072(n)][1024(k=d)] bf16
__global__ void repack_qkv_kernel(const float* __restrict__ wq,
                                  const float* __restrict__ wk,
                                  const float* __restrict__ wv,
                                  bf16* __restrict__ dst) {
  __shared__ float tile[64][65];
  const int dblk = blockIdx.x;  // 0..15 (d blocks)
  const int z = blockIdx.y;     // 0..47 = w*16+h
  const int w = z >> 4, h = z & 15;
  const float* src = (w == 0 ? wq : (w == 1 ? wk : wv)) + (size_t)h * Dc * HSc;
  const int tx = threadIdx.x, ty = threadIdx.y;
#pragma unroll
  for (int i = 0; i < 16; ++i)
    tile[ty + i * 4][tx] = src[(size_t)(dblk * 64 + ty + i * 4) * HSc + tx];
  __syncthreads();
#pragma unroll
  for (int i = 0; i < 16; ++i) {
    const int s = ty + i * 4;
    dst[((size_t)w * 1024 + h * 64 + s) * Dc + dblk * 64 + tx] = (bf16)tile[tx][s];
  }
}

// ---------------- generic [R][C] f32 -> [C][R] bf16 transpose
__global__ void transpose_to_bf16_kernel(const float* __restrict__ src,
                                         bf16* __restrict__ dst, int R, int C) {
  __shared__ float tile[64][65];
  const int r0 = blockIdx.x * 64, c0 = blockIdx.y * 64;
  const int tx = threadIdx.x, ty = threadIdx.y;
#pragma unroll
  for (int i = 0; i < 16; ++i)
    tile[ty + i * 4][tx] = src[(size_t)(r0 + ty + i * 4) * C + c0 + tx];
  __syncthreads();
#pragma unroll
  for (int i = 0; i < 16; ++i)
    dst[(size_t)(c0 + ty + i * 4) * R + r0 + tx] = (bf16)tile[tx][ty + i * 4];
}

// ---------------- LayerNorm row kernel: f32 in -> bf16 out
__global__ __launch_bounds__(256) void ln_kernel(const float* __restrict__ x,
                                                 const float* __restrict__ gam,
                                                 const float* __restrict__ bet,
                                                 bf16* __restrict__ out) {
  const int row = blockIdx.x;
  const int t = threadIdx.x;
  const float4 v = ((const float4*)(x + (size_t)row * Dc))[t];
  float s = v.x + v.y + v.z + v.w;
  float s2 = v.x * v.x + v.y * v.y + v.z * v.z + v.w * v.w;
#pragma unroll
  for (int m = 1; m < 64; m <<= 1) {
    s += __shfl_xor(s, m);
    s2 += __shfl_xor(s2, m);
  }
  __shared__ float red[8];
  const int wid = t >> 6;
  if ((t & 63) == 0) { red[wid * 2] = s; red[wid * 2 + 1] = s2; }
  __syncthreads();
  s = red[0] + red[2] + red[4] + red[6];
  s2 = red[1] + red[3] + red[5] + red[7];
  const float mean = s * (1.f / Dc);
  const float var = s2 * (1.f / Dc) - mean * mean;
  const float rstd = rsqrtf(var + 1e-5f);
  const float4 gv = ((const float4*)gam)[t];
  const float4 bv = ((const float4*)bet)[t];
  bf16x4 o;
  o[0] = (bf16)((v.x - mean) * rstd * gv.x + bv.x);
  o[1] = (bf16)((v.y - mean) * rstd * gv.y + bv.y);
  o[2] = (bf16)((v.z - mean) * rstd * gv.z + bv.z);
  o[3] = (bf16)((v.w - mean) * rstd * gv.w + bv.w);
  *(bf16x4*)(out + (size_t)row * Dc + t * 4) = o;
}

// ---------------- GEMM: C[M,N] = A[M,K](bf16) * BT[N,K](bf16), m97 structure.
template <int MODE, int KTOT, int NSTRIDE>
__global__ __launch_bounds__(256, 2) void gemm_kernel(
    const bf16* __restrict__ A, const bf16* __restrict__ BT,
    const float* __restrict__ bias, const float* __restrict__ resid,
    float* __restrict__ outf, bf16* __restrict__ outb,
    bf16* __restrict__ qo, bf16* __restrict__ ko, bf16* __restrict__ vto) {
  __shared__ __attribute__((aligned(16))) bf16 As[128 * 32];
  __shared__ __attribute__((aligned(16))) bf16 Bs[128 * 32];
  const int tid = threadIdx.x;
  const int wid = tid >> 6, lane = tid & 63;
  const int g = lane >> 4, c = lane & 15;
  const int wr = wid >> 1, wc = wid & 1;
  const int bm = blockIdx.x, bn = blockIdx.y;

  f32x4 acc[4][4];
#pragma unroll
  for (int i = 0; i < 4; ++i)
#pragma unroll
    for (int j = 0; j < 4; ++j)
#pragma unroll
      for (int r = 0; r < 4; ++r) acc[i][j][r] = 0.f;

  const bf16* gA = A + (size_t)(bm * 128 + wid * 32 + (lane >> 2)) * KTOT + (lane & 3) * 8;
  const bf16* gB = BT + (size_t)(bn * 128 + wid * 32 + (lane >> 2)) * KTOT + (lane & 3) * 8;
  bf16* lA0 = &As[(wid * 32) * 32];
  bf16* lA1 = &As[(wid * 32 + 16) * 32];
  bf16* lB0 = &Bs[(wid * 32) * 32];
  bf16* lB1 = &Bs[(wid * 32 + 16) * 32];

  for (int kt = 0; kt < KTOT / 32; ++kt) {
    load_lds16(gA, lA0);
    load_lds16(gA + (size_t)16 * KTOT, lA1);
    load_lds16(gB, lB0);
    load_lds16(gB + (size_t)16 * KTOT, lB1);
    gA += 32;
    gB += 32;
    __syncthreads();
    bf16x8 af[4], bfr[4];
#pragma unroll
    for (int mi = 0; mi < 4; ++mi)
      af[mi] = *(const bf16x8*)&As[(wr * 64 + mi * 16 + c) * 32 + g * 8];
#pragma unroll
    for (int ni = 0; ni < 4; ++ni)
      bfr[ni] = *(const bf16x8*)&Bs[(wc * 64 + ni * 16 + c) * 32 + g * 8];
#pragma unroll
    for (int mi = 0; mi < 4; ++mi)
#pragma unroll
      for (int ni = 0; ni < 4; ++ni)
        acc[mi][ni] =
            __builtin_amdgcn_mfma_f32_16x16x32_bf16(af[mi], bfr[ni], acc[mi][ni], 0, 0, 0);
    __syncthreads();
  }

#pragma unroll
  for (int ni = 0; ni < 4; ++ni) {
    const int n = bn * 128 + wc * 64 + ni * 16 + c;
    float bi = 0.f;
    if (MODE != 0) bi = bias[n];
#pragma unroll
    for (int mi = 0; mi < 4; ++mi) {
      const int m0 = bm * 128 + wr * 64 + mi * 16 + g * 4;
      if (MODE == 0) {
        const int w = n >> 10, n1 = n & 1023, h = n1 >> 6, sidx = n1 & 63;
        const int b = m0 >> 11, t0 = m0 & 2047;
        if (w == 0) {
#pragma unroll
          for (int r = 0; r < 4; ++r)
            qo[(size_t)(b * Hc + h) * (Tc * HSc) + (size_t)(t0 + r) * HSc + sidx] =
                (bf16)(acc[mi][ni][r] * 0.125f);
        } else if (w == 1) {
#pragma unroll
          for (int r = 0; r < 4; ++r)
            ko[(size_t)(b * Hc + h) * (Tc * HSc) + (size_t)(t0 + r) * HSc + sidx] =
                (bf16)acc[mi][ni][r];
        } else {
          bf16x4 pk;
#pragma unroll
          for (int r = 0; r < 4; ++r) pk[r] = (bf16)acc[mi][ni][r];
          *(bf16x4*)&vto[((size_t)(b * Hc + h) * HSc + sidx) * Tc + t0] = pk;
        }
      } else if (MODE == 1 || MODE == 3) {
#pragma unroll
        for (int r = 0; r < 4; ++r) {
          const size_t idx = (size_t)(m0 + r) * NSTRIDE + n;
          outf[idx] = acc[mi][ni][r] + bi + resid[idx];
        }
      } else {  // MODE 2
#pragma unroll
        for (int r = 0; r < 4; ++r)
          outb[(size_t)(m0 + r) * NSTRIDE + n] = (bf16)fmaxf(acc[mi][ni][r] + bi, 0.f);
      }
    }
  }
}

// ---------------- causal flash attention v3
// 4 waves/block; block covers two 128-row q-groups (pair 15-p, p) -> 34 kv-iters
// uniform. K/V tiles staged once per block into XOR-swizzled double-buffered LDS
// via global_load_lds (linear dest + inverse-swizzled global src, swizzled reads).
// q,k: [bh,t,hs] bf16 (q pre-scaled), vt: [bh,hs,t] bf16, ctx: [b*t, h*64+d] bf16
__global__ __launch_bounds__(256, 2) void attn_kernel(const bf16* __restrict__ q,
                                                      const bf16* __restrict__ k,
                                                      const bf16* __restrict__ vt,
                                                      bf16* __restrict__ ctx) {
  __shared__ __attribute__((aligned(16))) bf16 Kl[2][4096];  // 2 x 64x64 tile
  __shared__ __attribute__((aligned(16))) bf16 Vl[2][4096];
  __shared__ __attribute__((aligned(16))) bf16 P[4][32][72];
  const int d0 = blockIdx.x;
  const int L = (d0 & 7) * 64 + (d0 >> 3);  // XCD-grouped: 8 heads per XCD
  const int bh = L >> 3, p = L & 7;
  const int tid = threadIdx.x;
  const int wid = tid >> 6, lane = tid & 63;
  const int g = lane >> 4, c = lane & 15;
  const bf16* qh = q + (size_t)bh * Tc * HSc;
  const char* kh = (const char*)(k + (size_t)bh * Tc * HSc);
  const char* vh = (const char*)(vt + (size_t)bh * HSc * Tc);
  const int b = bh >> 4, h = bh & 15;

  // staging swizzle (per-lane constants): dest LDS byte o = call*1024 + lane*16,
  // row = o>>7, src byte = o ^ ((row&7)<<4)
  const int sw = ((lane >> 3) & 7) << 4;
  const int soK = (lane * 16) ^ sw;          // K: within-tile swizzled src offset
  const int vrow = lane >> 3;                // V: row within 8-row call chunk
  const int vcol = ((lane & 7) * 16) ^ sw;   // V: swizzled col-byte within row
  const int rsw = (c & 7) << 4;              // read-side swizzle (row&7 == c&7)

  for (int g2 = 0; g2 < 2; ++g2) {
    const int grp = g2 ? p : 15 - p;   // heavy group first
    const int ktB = 2 * grp + 1;       // block-level last kv tile
    const int ktW = 2 * grp + (wid >> 1);  // this wave's last kv tile
    const int row0 = grp * 128 + wid * 32;
    const bf16* qb = qh + (size_t)row0 * HSc;

    bf16x8 qf[2][2];
#pragma unroll
    for (int mi = 0; mi < 2; ++mi)
#pragma unroll
      for (int kk = 0; kk < 2; ++kk)
        qf[mi][kk] = *(const bf16x8*)&qb[(size_t)(mi * 16 + c) * HSc + kk * 32 + g * 8];

    f32x4 o[2][4];
    float m_[2][4], ls[2][4];
#pragma unroll
    for (int mi = 0; mi < 2; ++mi)
#pragma unroll
      for (int r = 0; r < 4; ++r) {
        m_[mi][r] = -1e30f;
        ls[mi][r] = 0.f;
#pragma unroll
        for (int di = 0; di < 4; ++di) o[mi][di][r] = 0.f;
      }

    auto stage = [&](int buf, int kt) {
      const char* kb = kh + (size_t)kt * 8192;   // contiguous 64x64 bf16 tile
      const char* vb = vh + (size_t)kt * 128;    // col offset into [64][Tc]
#pragma unroll
      for (int i = 0; i < 4; ++i) {
        const int idx = wid * 4 + i;  // 0..15: 8 K calls then 8 V calls
        if (idx < 8) {
          load_lds16(kb + idx * 1024 + soK, (char*)&Kl[buf][0] + idx * 1024);
        } else {
          const int j = idx - 8;
          load_lds16(vb + (size_t)(j * 8 + vrow) * (Tc * 2) + vcol,
                     (char*)&Vl[buf][0] + j * 1024);
        }
      }
    };

    stage(0, 0);
    __syncthreads();
    int cur = 0;
    for (int kt = 0; kt <= ktB; ++kt) {
      if (kt < ktB) stage(cur ^ 1, kt + 1);
      if (kt <= ktW) {
        const char* Kb = (const char*)&Kl[cur][0];
        bf16x8 kf[4][2];
#pragma unroll
        for (int ni = 0; ni < 4; ++ni)
#pragma unroll
          for (int kk = 0; kk < 2; ++kk)
            kf[ni][kk] = *(const bf16x8*)(Kb + (ni * 16 + c) * 128 +
                                          (((kk << 6) | (g << 4)) ^ rsw));
        f32x4 s[2][4];
#pragma unroll
        for (int mi = 0; mi < 2; ++mi)
#pragma unroll
          for (int ni = 0; ni < 4; ++ni)
#pragma unroll
            for (int r = 0; r < 4; ++r) s[mi][ni][r] = 0.f;
        __builtin_amdgcn_s_setprio(1);
#pragma unroll
        for (int kk = 0; kk < 2; ++kk)
#pragma unroll
          for (int mi = 0; mi < 2; ++mi)
#pragma unroll
            for (int ni = 0; ni < 4; ++ni)
              s[mi][ni] = __builtin_amdgcn_mfma_f32_16x16x32_bf16(qf[mi][kk], kf[ni][kk],
                                                                  s[mi][ni], 0, 0, 0);
        __builtin_amdgcn_s_setprio(0);

        if (kt == ktW) {  // causal mask on this wave's final tile
#pragma unroll
          for (int mi = 0; mi < 2; ++mi)
#pragma unroll
            for (int ni = 0; ni < 4; ++ni)
#pragma unroll
              for (int r = 0; r < 4; ++r) {
                const int row = row0 + mi * 16 + g * 4 + r;
                const int col = kt * 64 + ni * 16 + c;
                if (col > row) s[mi][ni][r] = -1e30f;
              }
        }

        // defer-max online softmax
        float pm[2][4];
        int need = 0;
#pragma unroll
        for (int mi = 0; mi < 2; ++mi)
#pragma unroll
          for (int r = 0; r < 4; ++r) {
            pm[mi][r] =
                fmaxf(fmaxf(s[mi][0][r], s[mi][1][r]), fmaxf(s[mi][2][r], s[mi][3][r]));
            need |= (pm[mi][r] > m_[mi][r] + 8.f) ? 1 : 0;
          }
        if (__any(need)) {
#pragma unroll
          for (int mi = 0; mi < 2; ++mi)
#pragma unroll
            for (int r = 0; r < 4; ++r) {
              float mx = pm[mi][r];
#pragma unroll
              for (int msk = 1; msk < 16; msk <<= 1) mx = fmaxf(mx, __shfl_xor(mx, msk));
              const float mn = fmaxf(m_[mi][r], mx);
              const float al = __expf(m_[mi][r] - mn);
              m_[mi][r] = mn;
              ls[mi][r] *= al;
#pragma unroll
              for (int di = 0; di < 4; ++di) o[mi][di][r] *= al;
            }
        }
#pragma unroll
        for (int mi = 0; mi < 2; ++mi)
#pragma unroll
          for (int r = 0; r < 4; ++r) {
            float ps = 0.f;
#pragma unroll
            for (int ni = 0; ni < 4; ++ni) {
              const float pv = __expf(s[mi][ni][r] - m_[mi][r]);
              ps += pv;
              P[wid][mi * 16 + g * 4 + r][ni * 16 + c] = (bf16)pv;
            }
            ls[mi][r] += ps;
          }
        asm volatile("s_waitcnt lgkmcnt(0)" ::: "memory");
        __builtin_amdgcn_sched_barrier(0);

        bf16x8 pf[2][2];
#pragma unroll
        for (int mi = 0; mi < 2; ++mi)
#pragma unroll
          for (int kk = 0; kk < 2; ++kk)
            pf[mi][kk] = *(const bf16x8*)&P[wid][mi * 16 + c][kk * 32 + g * 8];
        const char* Vb = (const char*)&Vl[cur][0];
#pragma unroll
        for (int di = 0; di < 4; ++di) {
          bf16x8 vf0 = *(const bf16x8*)(Vb + (di * 16 + c) * 128 + ((g << 4) ^ rsw));
          bf16x8 vf1 =
              *(const bf16x8*)(Vb + (di * 16 + c) * 128 + (((1 << 6) | (g << 4)) ^ rsw));
          __builtin_amdgcn_s_setprio(1);
#pragma unroll
          for (int mi = 0; mi < 2; ++mi) {
            o[mi][di] = __builtin_amdgcn_mfma_f32_16x16x32_bf16(pf[mi][0], vf0, o[mi][di], 0, 0, 0);
            o[mi][di] = __builtin_amdgcn_mfma_f32_16x16x32_bf16(pf[mi][1], vf1, o[mi][di], 0, 0, 0);
          }
          __builtin_amdgcn_s_setprio(0);
        }
      }
      __syncthreads();
      cur ^= 1;
    }

    // epilogue: reduce per-lane partial sums over 16 col-lanes, normalize, store
#pragma unroll
    for (int mi = 0; mi < 2; ++mi)
#pragma unroll
      for (int r = 0; r < 4; ++r) {
        float l = ls[mi][r];
#pragma unroll
        for (int msk = 1; msk < 16; msk <<= 1) l += __shfl_xor(l, msk);
        const float inv = 1.f / l;
        const int t = row0 + mi * 16 + g * 4 + r;
#pragma unroll
        for (int di = 0; di < 4; ++di)
          ctx[((size_t)(b * Tc + t)) * Dc + h * 64 + di * 16 + c] =
              (bf16)(o[mi][di][r] * inv);
      }
  }
}

// ---------------- launch ----------------
extern "C" void kernel_launch(void* const* d_in, const int* in_sizes, int n_in,
                              void* d_out, int out_size, void* d_ws, size_t ws_size,
                              hipStream_t stream) {
  (void)in_sizes; (void)n_in; (void)out_size; (void)ws_size;
  const float* x      = (const float*)d_in[0];
  const float* ln1_g  = (const float*)d_in[1];
  const float* ln1_b  = (const float*)d_in[2];
  const float* wq     = (const float*)d_in[3];
  const float* wk     = (const float*)d_in[4];
  const float* wv     = (const float*)d_in[5];
  const float* w_proj = (const float*)d_in[6];
  const float* b_proj = (const float*)d_in[7];
  const float* ln2_g  = (const float*)d_in[8];
  const float* ln2_b  = (const float*)d_in[9];
  const float* w1     = (const float*)d_in[10];
  const float* b1     = (const float*)d_in[11];
  const float* w2     = (const float*)d_in[12];
  const float* b2     = (const float*)d_in[13];
  float* out = (float*)d_out;
  char* ws = (char*)d_ws;

  bf16* qbuf   = (bf16*)(ws + 0);          // 16777216
  bf16* kbuf   = (bf16*)(ws + 16777216);   // 16777216
  bf16* vtbuf  = (bf16*)(ws + 33554432);   // 16777216
  bf16* ctxbuf = (bf16*)(ws + 50331648);   // 16777216
  bf16* wqkvT  = (bf16*)(ws + 67108864);   // 6291456
  bf16* hbuf   = (bf16*)(ws + 0);          // 67108864 (aliases q/k/vt/ctx, dead by FFN1)
  bf16* wprojT = (bf16*)(ws + 73400320);   // 2097152
  bf16* w1T    = (bf16*)(ws + 75497472);   // 8388608
  bf16* w2T    = (bf16*)(ws + 83886080);   // 8388608
  bf16* xn     = (bf16*)(ws + 92274688);   // 16777216
  float* x1buf = (float*)(ws + 109051904); // 33554432

  repack_qkv_kernel<<<dim3(16, 48), dim3(64, 4), 0, stream>>>(wq, wk, wv, wqkvT);
  transpose_to_bf16_kernel<<<dim3(16, 16), dim3(64, 4), 0, stream>>>(w_proj, wprojT, 1024, 1024);
  transpose_to_bf16_kernel<<<dim3(16, 64), dim3(64, 4), 0, stream>>>(w1, w1T, 1024, 4096);
  transpose_to_bf16_kernel<<<dim3(64, 16), dim3(64, 4), 0, stream>>>(w2, w2T, 4096, 1024);

  ln_kernel<<<Mrows, 256, 0, stream>>>(x, ln1_g, ln1_b, xn);
  gemm_kernel<0, 1024, 0><<<dim3(64, 24), 256, 0, stream>>>(
      xn, wqkvT, nullptr, nullptr, nullptr, nullptr, qbuf, kbuf, vtbuf);
  attn_kernel<<<512, 256, 0, stream>>>(qbuf, kbuf, vtbuf, ctxbuf);
  gemm_kernel<1, 1024, 1024><<<dim3(64, 8), 256, 0, stream>>>(
      ctxbuf, wprojT, b_proj, x, x1buf, nullptr, nullptr, nullptr, nullptr);
  ln_kernel<<<Mrows, 256, 0, stream>>>(x1buf, ln2_g, ln2_b, xn);
  gemm_kernel<2, 1024, 4096><<<dim3(64, 32), 256, 0, stream>>>(
      xn, w1T, b1, nullptr, nullptr, hbuf, nullptr, nullptr, nullptr);
  gemm_kernel<3, 4096, 1024><<<dim3(64, 8), 256, 0, stream>>>(
      hbuf, w2T, b2, x1buf, out, nullptr, nullptr, nullptr, nullptr);
}